// Round 9
// baseline (267.462 us; speedup 1.0000x reference)
//
#include <hip/hip_runtime.h>

#define LEAKY(v) ((v) > 0.0f ? (v) : 0.01f * (v))
#define NBUK_MAX 512  // supports N <= 131072 (bucket = dst >> 8); N < 2^24 for packing

typedef __attribute__((ext_vector_type(8))) short bf16x8;   // 8 bf16 = 4 VGPRs
typedef __attribute__((ext_vector_type(4))) float f32x4;    // MFMA accumulator

// ---- bf16 helpers ----------------------------------------------------------
__device__ __forceinline__ unsigned short f2bf(float f) {
    unsigned u = __float_as_uint(f);
    u += 0x7fffu + ((u >> 16) & 1u);  // round-to-nearest-even
    return (unsigned short)(u >> 16);
}
__device__ __forceinline__ unsigned pack2bf(float lo, float hi) {
    return (unsigned)f2bf(lo) | ((unsigned)f2bf(hi) << 16);
}
__device__ __forceinline__ float4 bf4_to_f4(uint2 u) {
    float4 r;
    r.x = __uint_as_float(u.x << 16);
    r.y = __uint_as_float(u.x & 0xffff0000u);
    r.z = __uint_as_float(u.y << 16);
    r.w = __uint_as_float(u.y & 0xffff0000u);
    return r;
}

// ---------------------------------------------------------------------------
// int64-vs-int32 edge_index detection.
// ---------------------------------------------------------------------------
__device__ __forceinline__ int detect_is64(const unsigned* ei, int E) {
    __shared__ int is64_s;
    if (threadIdx.x == 0) {
        int z = 1;
        int limit = 2 * E < 128 ? 2 * E : 128;
        for (int i = 1; i < limit; i += 2)
            if (ei[i] != 0u) { z = 0; break; }
        is64_s = z;
    }
    __syncthreads();
    return is64_s;
}

// ---------------------------------------------------------------------------
// Pass A: decode edge_index -> s32/d32 (coalesced) + per-block bucket counts.
// ---------------------------------------------------------------------------
__global__ __launch_bounds__(256) void bucket_count_kernel(
    const unsigned* __restrict__ ei, int* __restrict__ s32, int* __restrict__ d32,
    int* __restrict__ gcount, int E, int nblk, int nbuk, int ch) {
    __shared__ int hist[NBUK_MAX];
    int is64 = detect_is64(ei, E);
    for (int i = threadIdx.x; i < nbuk; i += 256) hist[i] = 0;
    __syncthreads();
    int base = blockIdx.x * ch;
    int lim = min(base + ch, E);
    for (int e = base + threadIdx.x; e < lim; e += 256) {
        int s, d;
        if (is64) {
            s = (int)ei[2 * (size_t)e];
            d = (int)ei[2 * (size_t)E + 2 * (size_t)e];
        } else {
            s = (int)ei[e];
            d = (int)ei[(size_t)E + e];
        }
        s32[e] = s;
        d32[e] = d;
        atomicAdd(&hist[d >> 8], 1);
    }
    __syncthreads();
    for (int i = threadIdx.x; i < nbuk; i += 256)
        gcount[(size_t)i * nblk + blockIdx.x] = hist[i];
}

// Pass B1: per-bucket totals (one block per bucket, parallel tree reduce).
__global__ __launch_bounds__(256) void bucket_total_kernel(
    const int* __restrict__ gcount, int* __restrict__ btot, int nblk) {
    __shared__ int s[256];
    int sum = 0;
    for (int i = threadIdx.x; i < nblk; i += 256)
        sum += gcount[(size_t)blockIdx.x * nblk + i];
    s[threadIdx.x] = sum;
    __syncthreads();
    for (int off = 128; off > 0; off >>= 1) {
        if (threadIdx.x < off) s[threadIdx.x] += s[threadIdx.x + off];
        __syncthreads();
    }
    if (threadIdx.x == 0) btot[blockIdx.x] = s[0];
}

// Pass B2: exclusive scan of bucket totals -> bbase[0..nbuk], + row_ofs[N]=E.
__global__ __launch_bounds__(512) void scan_btot_kernel(
    const int* __restrict__ btot, int* __restrict__ bbase,
    int* __restrict__ row_ofs, int nbuk, int N, int E) {
    __shared__ int s[512];
    int t = threadIdx.x;
    int v = (t < nbuk) ? btot[t] : 0;
    s[t] = v;
    __syncthreads();
    for (int off = 1; off < 512; off <<= 1) {
        int add = (t >= off) ? s[t - off] : 0;
        __syncthreads();
        s[t] += add;
        __syncthreads();
    }
    if (t < nbuk) bbase[t] = s[t] - v;
    if (t == 0) { bbase[nbuk] = E; row_ofs[N] = E; }
}

// Pass B3: per-bucket exclusive scan of gcount row + bucket base (in place).
__global__ __launch_bounds__(256) void scan_gcount_kernel(
    int* __restrict__ gcount, const int* __restrict__ bbase, int nblk) {
    __shared__ int s[256];
    int t = threadIdx.x;
    int v = (t < nblk) ? gcount[(size_t)blockIdx.x * nblk + t] : 0;
    s[t] = v;
    __syncthreads();
    for (int off = 1; off < 256; off <<= 1) {
        int add = (t >= off) ? s[t - off] : 0;
        __syncthreads();
        s[t] += add;
        __syncthreads();
    }
    if (t < nblk)
        gcount[(size_t)blockIdx.x * nblk + t] = bbase[blockIdx.x] + s[t] - v;
}

// Pass C: scatter edges into bucket-grouped PACKED es_tmp = (d&255)<<24 | src.
__global__ __launch_bounds__(256) void bucket_scatter_kernel(
    const int* __restrict__ s32, const int* __restrict__ d32,
    const int* __restrict__ gofs, unsigned* __restrict__ es_tmp,
    int E, int nblk, int nbuk, int ch) {
    __shared__ int cur[NBUK_MAX];
    for (int i = threadIdx.x; i < nbuk; i += 256)
        cur[i] = gofs[(size_t)i * nblk + blockIdx.x];
    __syncthreads();
    int base = blockIdx.x * ch;
    int lim = min(base + ch, E);
    for (int e = base + threadIdx.x; e < lim; e += 256) {
        int s = s32[e], d = d32[e];
        int p = atomicAdd(&cur[d >> 8], 1);
        es_tmp[p] = ((unsigned)(d & 255) << 24) | (unsigned)s;
    }
}

// Pass D (+cvt fused): per-bucket node counting sort -> es, row_ofs, dinv;
// then converts this bucket's 256 x-rows to xb = bf16(x * dinv).
__global__ __launch_bounds__(256) void bucket_sortcvt_kernel(
    const unsigned* __restrict__ es_tmp, const int* __restrict__ bbase,
    int* __restrict__ es, int* __restrict__ row_ofs, float* __restrict__ dinv,
    const float* __restrict__ x, ushort4* __restrict__ xb, int N) {
    __shared__ int hist[256];
    __shared__ int lofs[256];
    __shared__ float sdinv[256];
    int b = blockIdx.x;
    int t = threadIdx.x;
    int beg = bbase[b], end = bbase[b + 1];
    hist[t] = 0;
    __syncthreads();
    for (int j = beg + t; j < end; j += 256)
        atomicAdd(&hist[es_tmp[j] >> 24], 1);
    __syncthreads();
    int v = hist[t];
    lofs[t] = v;
    __syncthreads();
    for (int off = 1; off < 256; off <<= 1) {
        int add = (t >= off) ? lofs[t - off] : 0;
        __syncthreads();
        lofs[t] += add;
        __syncthreads();
    }
    int excl = lofs[t] - v;
    int node = (b << 8) + t;
    float dv = rsqrtf((float)v + 1.0f);
    if (node <= N) row_ofs[node] = beg + excl;
    if (node < N) dinv[node] = dv;
    sdinv[t] = dv;
    __syncthreads();
    lofs[t] = beg + excl;  // running cursor
    __syncthreads();
    for (int j = beg + t; j < end; j += 256) {
        unsigned ed = es_tmp[j];
        int p = atomicAdd(&lofs[ed >> 24], 1);
        es[p] = (int)(ed & 0xFFFFFFu);
    }
    // cvt: xb rows for this bucket's nodes (16 float4-quads per node)
    int qbase = (b << 8) * 16;
    for (int q = t; q < 256 * 16; q += 256) {
        int nl = q >> 4;
        int n = (b << 8) + nl;
        if (n >= N) break;
        float dn = sdinv[nl];
        float4 vv = ((const float4*)x)[qbase + q];
        ushort4 o;
        o.x = f2bf(vv.x * dn); o.y = f2bf(vv.y * dn);
        o.z = f2bf(vv.z * dn); o.w = f2bf(vv.w * dn);
        xb[qbase + q] = o;
    }
}

// ---------------------------------------------------------------------------
// W-fragment prepack for MFMA GEMMs, with hi/lo bf16 split (W ~ hi + lo so
// the MFMA pair reproduces fp32-W precision).
// Fragment order: f = (mt*NKC + kc)*2 + s; per frag: 64 lanes x 8 bf16.
// Element (lane, j): k = kc*32 + (lane>>4)*8 + j, col = mt*16 + (lane&15).
// Region G1 (W1 64x80, NKC=2, NMT=5): units 0..1279.
// Region G2 (W2 80x40, NKC=3, NMT=3): units 1280..2431 (zero-padded k/col).
// ---------------------------------------------------------------------------
__global__ __launch_bounds__(256) void prep_wfrags_kernel(
    const float* __restrict__ W1, const float* __restrict__ W2,
    unsigned short* __restrict__ wfrag) {
    int t = blockIdx.x * 256 + threadIdx.x;
    if (t >= 2432) return;
    const float* W;
    int u, NKC, M, K;
    if (t < 1280) { u = t; W = W1; NKC = 2; M = 80; K = 64; }
    else          { u = t - 1280; W = W2; NKC = 3; M = 40; K = 80; }
    int f = u >> 6, lane = u & 63;
    int s = f & 1, mtkc = f >> 1;
    int kc = mtkc % NKC, mt = mtkc / NKC;
    int col = mt * 16 + (lane & 15);
#pragma unroll
    for (int j = 0; j < 8; ++j) {
        int k = kc * 32 + ((lane >> 4) << 3) + j;
        float w = (k < K && col < M) ? W[k * M + col] : 0.0f;
        unsigned short hi = f2bf(w);
        unsigned short v = s ? f2bf(w - __uint_as_float((unsigned)hi << 16)) : hi;
        wfrag[(size_t)t * 8 + j] = v;
    }
}

// ---------------------------------------------------------------------------
// FUSED L1, K-PAIR SPLIT: gather64(xb) + MFMA GEMM1 (+b1, leaky) -> A [N][80].
// 512 threads = 8 waves = 4 tile-pairs. Each 16-node tile is walked by TWO
// waves over interleaved edge halves (even/odd); fp32 partials exchanged via
// padded LDS; wave-0 of each pair runs MFMA + epilogue. Doubles resident
// waves (latency hiding) and halves each wave's serial edge chain.
// ---------------------------------------------------------------------------
__global__ __launch_bounds__(512) void l1_fused_kernel(
    const unsigned short* __restrict__ xb, const int* __restrict__ es,
    const int* __restrict__ row_ofs, const float* __restrict__ dinv,
    const unsigned short* __restrict__ wfrag, const float* __restrict__ b1,
    unsigned short* __restrict__ out, int N) {
    constexpr int NFR = 20;  // 5 mt x 2 kc x 2 (hi/lo)
    __shared__ bf16x8 wlds[NFR * 64];
    __shared__ float pbuf[4][64][17];  // +1 pad: conflict-free b32 exchange
    for (int i = threadIdx.x; i < NFR * 64; i += 512) {
        int f = i >> 6, ln = i & 63;
        wlds[f * 64 + (ln ^ (ln >> 3))] = *(const bf16x8*)&wfrag[(size_t)i * 8];
    }
    __syncthreads();
    int wv = threadIdx.x >> 6;      // 0..7
    int pair = wv >> 1, half = wv & 1;
    int tile = blockIdx.x * 4 + pair;
    int ntiles = (N + 15) >> 4;
    int lane = threadIdx.x & 63;
    int row = lane & 15, kid = lane >> 4;
    int lidx = lane ^ (lane >> 3);
    int base = tile * 16;
    int node = base + row;
    bool act = (tile < ntiles) && (node < N);
    int beg = 0, end = 0;
    float dd = 0.f;
    if (act) {
        beg = row_ofs[node];
        end = row_ofs[node + 1];
        dd = dinv[node];
    }
    const char* xbb = (const char*)xb;
    const int o0 = kid * 16;       // byte offset of chunk kid
    const int o1 = 64 + kid * 16;  // byte offset of chunk kid+4
    float4 aL0 = make_float4(0.f, 0.f, 0.f, 0.f);
    float4 aL1 = make_float4(0.f, 0.f, 0.f, 0.f);
    float4 aH0 = make_float4(0.f, 0.f, 0.f, 0.f);
    float4 aH1 = make_float4(0.f, 0.f, 0.f, 0.f);
#define ACCU(u, c0, c1)                                             \
    {                                                               \
        float4 lo_ = bf4_to_f4(make_uint2((u).x, (u).y));           \
        float4 hi_ = bf4_to_f4(make_uint2((u).z, (u).w));           \
        c0.x += lo_.x; c0.y += lo_.y; c0.z += lo_.z; c0.w += lo_.w; \
        c1.x += hi_.x; c1.y += hi_.y; c1.z += hi_.z; c1.w += hi_.w; \
    }
    int j = beg + half;            // interleaved halves: half walks j, j+2, ...
    for (; j + 6 < end; j += 8) {
        int s0 = es[j], s1 = es[j + 2], s2 = es[j + 4], s3 = es[j + 6];
        const char* p0 = xbb + (size_t)s0 * 128;
        const char* p1 = xbb + (size_t)s1 * 128;
        const char* p2 = xbb + (size_t)s2 * 128;
        const char* p3 = xbb + (size_t)s3 * 128;
        uint4 u00 = *(const uint4*)(p0 + o0);
        uint4 u01 = *(const uint4*)(p0 + o1);
        uint4 u10 = *(const uint4*)(p1 + o0);
        uint4 u11 = *(const uint4*)(p1 + o1);
        uint4 u20 = *(const uint4*)(p2 + o0);
        uint4 u21 = *(const uint4*)(p2 + o1);
        uint4 u30 = *(const uint4*)(p3 + o0);
        uint4 u31 = *(const uint4*)(p3 + o1);
        ACCU(u00, aL0, aL1) ACCU(u01, aH0, aH1)
        ACCU(u10, aL0, aL1) ACCU(u11, aH0, aH1)
        ACCU(u20, aL0, aL1) ACCU(u21, aH0, aH1)
        ACCU(u30, aL0, aL1) ACCU(u31, aH0, aH1)
    }
    for (; j < end; j += 2) {
        int s0 = es[j];
        const char* p0 = xbb + (size_t)s0 * 128;
        uint4 u00 = *(const uint4*)(p0 + o0);
        uint4 u01 = *(const uint4*)(p0 + o1);
        ACCU(u00, aL0, aL1) ACCU(u01, aH0, aH1)
    }
    if (act && half == 0) {  // self term (once per node)
        const char* ps = xbb + (size_t)node * 128;
        uint4 us0 = *(const uint4*)(ps + o0);
        uint4 us1 = *(const uint4*)(ps + o1);
        ACCU(us0, aL0, aL1) ACCU(us1, aH0, aH1)
    }
#undef ACCU
    // exchange partials: half==1 writes, half==0 adds
    if (half == 1) {
        float* pb = pbuf[pair][lane];
        pb[0] = aL0.x; pb[1] = aL0.y; pb[2] = aL0.z; pb[3] = aL0.w;
        pb[4] = aL1.x; pb[5] = aL1.y; pb[6] = aL1.z; pb[7] = aL1.w;
        pb[8] = aH0.x; pb[9] = aH0.y; pb[10] = aH0.z; pb[11] = aH0.w;
        pb[12] = aH1.x; pb[13] = aH1.y; pb[14] = aH1.z; pb[15] = aH1.w;
    }
    __syncthreads();
    if (half == 1) return;
    {
        const float* pb = pbuf[pair][lane];
        aL0.x += pb[0]; aL0.y += pb[1]; aL0.z += pb[2]; aL0.w += pb[3];
        aL1.x += pb[4]; aL1.y += pb[5]; aL1.z += pb[6]; aL1.w += pb[7];
        aH0.x += pb[8]; aH0.y += pb[9]; aH0.z += pb[10]; aH0.w += pb[11];
        aH1.x += pb[12]; aH1.y += pb[13]; aH1.z += pb[14]; aH1.w += pb[15];
    }
    // pack A-fragments: a0 = chunk kid (kc=0), a1 = chunk kid+4 (kc=1)
    bf16x8 a0, a1;
    a0[0] = (short)f2bf(aL0.x * dd); a0[1] = (short)f2bf(aL0.y * dd);
    a0[2] = (short)f2bf(aL0.z * dd); a0[3] = (short)f2bf(aL0.w * dd);
    a0[4] = (short)f2bf(aL1.x * dd); a0[5] = (short)f2bf(aL1.y * dd);
    a0[6] = (short)f2bf(aL1.z * dd); a0[7] = (short)f2bf(aL1.w * dd);
    a1[0] = (short)f2bf(aH0.x * dd); a1[1] = (short)f2bf(aH0.y * dd);
    a1[2] = (short)f2bf(aH0.z * dd); a1[3] = (short)f2bf(aH0.w * dd);
    a1[4] = (short)f2bf(aH1.x * dd); a1[5] = (short)f2bf(aH1.y * dd);
    a1[6] = (short)f2bf(aH1.z * dd); a1[7] = (short)f2bf(aH1.w * dd);

    f32x4 acc[5];
#pragma unroll
    for (int mt = 0; mt < 5; ++mt) acc[mt] = (f32x4){0.f, 0.f, 0.f, 0.f};
#pragma unroll
    for (int mt = 0; mt < 5; ++mt) {
        acc[mt] = __builtin_amdgcn_mfma_f32_16x16x32_bf16(
            a0, wlds[((mt * 2 + 0) * 2 + 0) * 64 + lidx], acc[mt], 0, 0, 0);
        acc[mt] = __builtin_amdgcn_mfma_f32_16x16x32_bf16(
            a0, wlds[((mt * 2 + 0) * 2 + 1) * 64 + lidx], acc[mt], 0, 0, 0);
        acc[mt] = __builtin_amdgcn_mfma_f32_16x16x32_bf16(
            a1, wlds[((mt * 2 + 1) * 2 + 0) * 64 + lidx], acc[mt], 0, 0, 0);
        acc[mt] = __builtin_amdgcn_mfma_f32_16x16x32_bf16(
            a1, wlds[((mt * 2 + 1) * 2 + 1) * 64 + lidx], acc[mt], 0, 0, 0);
    }
#pragma unroll
    for (int mt = 0; mt < 5; ++mt) {
        int col = mt * 16 + (lane & 15);
        float bb = b1[col];
#pragma unroll
        for (int r = 0; r < 4; ++r) {
            int orow = base + kid * 4 + r;
            if (orow < N) {
                float v = acc[mt][r] + bb;
                v = LEAKY(v);
                out[(size_t)orow * 80 + col] = f2bf(v);
            }
        }
    }
}

// ---------------------------------------------------------------------------
// F=40 bf16 gather, GROUP-PER-NODE, unroll x4 (4 loads in flight):
// 12 groups x 5 lanes x uint4 (16B) = one 80B row per group; lanes 60-63 idle.
// ---------------------------------------------------------------------------
template <bool BIAS, bool PRESCALE_LEAKY>
__global__ __launch_bounds__(256) void gather40_bf16_kernel(
    const unsigned short* __restrict__ hb, const int* __restrict__ es,
    const int* __restrict__ row_ofs, const float* __restrict__ dinv,
    const float* __restrict__ b, unsigned short* __restrict__ agg, int N) {
    int wid = (blockIdx.x * blockDim.x + threadIdx.x) >> 6;
    int lane = threadIdx.x & 63;
    int g = lane / 5;           // 0..12 (lanes 60-63: g==12, inactive)
    int l = lane - g * 5;       // 0..4
    int node = wid * 12 + g;
    bool active = (g < 12) && (node < N);
    int beg = 0, end = 0;
    float dd = 0.f;
    if (active) {
        beg = row_ofs[node];
        end = row_ofs[node + 1];
        dd = dinv[node];
    }
    float4 aL = make_float4(0.f, 0.f, 0.f, 0.f);
    float4 aH = make_float4(0.f, 0.f, 0.f, 0.f);
#define ACC40(u)                                                    \
    {                                                               \
        float4 lo_ = bf4_to_f4(make_uint2((u).x, (u).y));           \
        float4 hi_ = bf4_to_f4(make_uint2((u).z, (u).w));           \
        aL.x += lo_.x; aL.y += lo_.y; aL.z += lo_.z; aL.w += lo_.w; \
        aH.x += hi_.x; aH.y += hi_.y; aH.z += hi_.z; aH.w += hi_.w; \
    }
    int j = beg;
    for (; j + 4 <= end; j += 4) {
        int s0 = es[j], s1 = es[j + 1], s2 = es[j + 2], s3 = es[j + 3];
        uint4 h0 = *(const uint4*)&hb[(size_t)s0 * 40 + 8 * l];
        uint4 h1 = *(const uint4*)&hb[(size_t)s1 * 40 + 8 * l];
        uint4 h2 = *(const uint4*)&hb[(size_t)s2 * 40 + 8 * l];
        uint4 h3 = *(const uint4*)&hb[(size_t)s3 * 40 + 8 * l];
        ACC40(h0) ACC40(h1) ACC40(h2) ACC40(h3)
    }
    for (; j < end; ++j) {
        int s0 = es[j];
        uint4 h0 = *(const uint4*)&hb[(size_t)s0 * 40 + 8 * l];
        ACC40(h0)
    }
#undef ACC40
    if (active) {
        uint4 sr = *(const uint4*)&hb[(size_t)node * 40 + 8 * l];
        float4 sL = bf4_to_f4(make_uint2(sr.x, sr.y));
        float4 sH = bf4_to_f4(make_uint2(sr.z, sr.w));
        float r0 = (aL.x + sL.x) * dd, r1 = (aL.y + sL.y) * dd;
        float r2 = (aL.z + sL.z) * dd, r3 = (aL.w + sL.w) * dd;
        float r4 = (aH.x + sH.x) * dd, r5 = (aH.y + sH.y) * dd;
        float r6 = (aH.z + sH.z) * dd, r7 = (aH.w + sH.w) * dd;
        if (BIAS) {
            float4 b0 = *(const float4*)&b[8 * l];
            float4 b1 = *(const float4*)&b[8 * l + 4];
            r0 += b0.x; r1 += b0.y; r2 += b0.z; r3 += b0.w;
            r4 += b1.x; r5 += b1.y; r6 += b1.z; r7 += b1.w;
        }
        if (PRESCALE_LEAKY) {
            r0 = LEAKY(r0) * dd; r1 = LEAKY(r1) * dd;
            r2 = LEAKY(r2) * dd; r3 = LEAKY(r3) * dd;
            r4 = LEAKY(r4) * dd; r5 = LEAKY(r5) * dd;
            r6 = LEAKY(r6) * dd; r7 = LEAKY(r7) * dd;
        }
        uint4 o;
        o.x = pack2bf(r0, r1); o.y = pack2bf(r2, r3);
        o.z = pack2bf(r4, r5); o.w = pack2bf(r6, r7);
        *(uint4*)&agg[(size_t)node * 40 + 8 * l] = o;
    }
}

// ---------------------------------------------------------------------------
// MFMA GEMM (GEMM2): out[n][m] = epilogue( sum_k X[n][k]*W[k][m] ).
// ---------------------------------------------------------------------------
template <int KBF, int M, int NKC, int NMT, bool LEAKY_OUT, bool BIAS, bool SCALE>
__global__ __launch_bounds__(256) void gemm_mfma_bf16(
    const unsigned short* __restrict__ X, const unsigned short* __restrict__ wfrag,
    const float* __restrict__ bvec, const float* __restrict__ dinv,
    unsigned short* __restrict__ out, int N) {
    static_assert(KBF <= NKC * 32 && M <= NMT * 16, "tile coverage");
    constexpr int NFR = NMT * NKC * 2;
    __shared__ bf16x8 wlds[NFR * 64];
    for (int i = threadIdx.x; i < NFR * 64; i += 256) {
        int f = i >> 6, ln = i & 63;
        wlds[f * 64 + (ln ^ (ln >> 3))] = *(const bf16x8*)&wfrag[(size_t)i * 8];
    }
    __syncthreads();
    int wid = blockIdx.x * 4 + (threadIdx.x >> 6);
    int ntiles = (N + 15) >> 4;
    if (wid >= ntiles) return;
    int lane = threadIdx.x & 63;
    int kid = lane >> 4;                 // 0..3
    int lidx = lane ^ (lane >> 3);       // LDS swizzle index
    int base = wid * 16;
    int arow = base + (lane & 15);
    if (arow >= N) arow = N - 1;

    bf16x8 a[NKC];
#pragma unroll
    for (int kc = 0; kc < NKC; ++kc) {
        int k0 = kc * 32 + kid * 8;
        if (k0 < KBF)
            a[kc] = *(const bf16x8*)&X[(size_t)arow * KBF + k0];
        else
            a[kc] = (bf16x8){0, 0, 0, 0, 0, 0, 0, 0};
    }
    f32x4 acc[NMT];
#pragma unroll
    for (int mt = 0; mt < NMT; ++mt) acc[mt] = (f32x4){0.f, 0.f, 0.f, 0.f};
#pragma unroll
    for (int mt = 0; mt < NMT; ++mt) {
#pragma unroll
        for (int kc = 0; kc < NKC; ++kc) {
            acc[mt] = __builtin_amdgcn_mfma_f32_16x16x32_bf16(
                a[kc], wlds[((mt * NKC + kc) * 2 + 0) * 64 + lidx], acc[mt], 0, 0, 0);
            acc[mt] = __builtin_amdgcn_mfma_f32_16x16x32_bf16(
                a[kc], wlds[((mt * NKC + kc) * 2 + 1) * 64 + lidx], acc[mt], 0, 0, 0);
        }
    }
    float dv[4];
#pragma unroll
    for (int r = 0; r < 4; ++r)
        dv[r] = SCALE ? dinv[min(base + kid * 4 + r, N - 1)] : 1.0f;
#pragma unroll
    for (int mt = 0; mt < NMT; ++mt) {
        int col = mt * 16 + (lane & 15);
        if (col >= M) continue;
        float bb = BIAS ? bvec[col] : 0.0f;
#pragma unroll
        for (int r = 0; r < 4; ++r) {
            int orow = base + kid * 4 + r;
            if (orow < N) {
                float v = acc[mt][r] + bb;
                if (LEAKY_OUT) v = LEAKY(v);
                if (SCALE) v *= dv[r];
                out[(size_t)orow * M + col] = f2bf(v);
            }
        }
    }
}

// ---------------------------------------------------------------------------
// Fused L3-GEMM (40->50, +b3) + leaky + head (50x10, +bl) + log_softmax.
// ---------------------------------------------------------------------------
__global__ __launch_bounds__(256) void l3head_kernel(
    const unsigned short* __restrict__ P, const float* __restrict__ W3,
    const float* __restrict__ b3, const float* __restrict__ Wl,
    const float* __restrict__ bl, float* __restrict__ out, int N) {
    __shared__ float w3s[40 * 50];
    __shared__ float b3s[50];
    __shared__ float wls[50 * 10];
    __shared__ float bls[10];
    for (int i = threadIdx.x; i < 2000; i += 256) w3s[i] = W3[i];
    for (int i = threadIdx.x; i < 500; i += 256) wls[i] = Wl[i];
    if (threadIdx.x < 50) b3s[threadIdx.x] = b3[threadIdx.x];
    if (threadIdx.x < 10) bls[threadIdx.x] = bl[threadIdx.x];
    __syncthreads();
    int n = blockIdx.x * blockDim.x + threadIdx.x;
    if (n >= N) return;

    float p[40];
    const uint2* pr = (const uint2*)(P + (size_t)n * 40);
#pragma unroll
    for (int q = 0; q < 10; ++q) {
        float4 t = bf4_to_f4(pr[q]);
        p[4 * q + 0] = t.x; p[4 * q + 1] = t.y; p[4 * q + 2] = t.z; p[4 * q + 3] = t.w;
    }
    float logits[10];
#pragma unroll
    for (int j = 0; j < 10; ++j) logits[j] = bls[j];
    for (int m = 0; m < 50; ++m) {
        float acc = b3s[m];
#pragma unroll
        for (int k = 0; k < 40; ++k) acc = fmaf(p[k], w3s[k * 50 + m], acc);
        float v = LEAKY(acc);
#pragma unroll
        for (int j = 0; j < 10; ++j) logits[j] = fmaf(v, wls[m * 10 + j], logits[j]);
    }
    float mx = logits[0];
#pragma unroll
    for (int j = 1; j < 10; ++j) mx = fmaxf(mx, logits[j]);
    float s = 0.0f;
#pragma unroll
    for (int j = 0; j < 10; ++j) s += __expf(logits[j] - mx);
    float lse = __logf(s) + mx;
    float* op = out + (size_t)n * 10;
#pragma unroll
    for (int j = 0; j < 10; ++j) op[j] = logits[j] - lse;
}

extern "C" void kernel_launch(void* const* d_in, const int* in_sizes, int n_in,
                              void* d_out, int out_size, void* d_ws, size_t ws_size,
                              hipStream_t stream) {
    const float* x  = (const float*)d_in[0];
    const unsigned* ei = (const unsigned*)d_in[1];
    const float* W1 = (const float*)d_in[2];
    const float* b1 = (const float*)d_in[3];
    const float* W2 = (const float*)d_in[4];
    const float* b2 = (const float*)d_in[5];
    const float* W3 = (const float*)d_in[6];
    const float* b3 = (const float*)d_in[7];
    const float* Wl = (const float*)d_in[8];
    const float* bl = (const float*)d_in[9];
    float* out = (float*)d_out;

    const int N = in_sizes[0] / 64;
    const int E = in_sizes[1] / 2;

    // counting-sort geometry
    int ch = 4096;
    int nblk = (E + ch - 1) / ch;
    if (nblk > 256) { ch = (E + 255) / 256; nblk = (E + ch - 1) / ch; }
    const int nbuk = (N + 255) >> 8;  // <= 512

    char* wp = (char*)d_ws;
    auto alloc = [&](size_t bytes) {
        char* p = wp;
        wp += (bytes + 255) & ~(size_t)255;
        return p;
    };
    int*   es      = (int*)alloc((size_t)E * 4);
    float* dinv    = (float*)alloc((size_t)N * 4);
    int*   row_ofs = (int*)alloc((size_t)(N + 1) * 4);
    int*   gcount  = (int*)alloc((size_t)nbuk * nblk * 4);
    int*   btot    = (int*)alloc((size_t)NBUK_MAX * 4);
    int*   bbase   = (int*)alloc((size_t)(NBUK_MAX + 1) * 4);
    unsigned short* wfrag = (unsigned short*)alloc((size_t)2432 * 8 * 2);  // 38 KB
    char*  Pr      = (char*)alloc((size_t)N * 64 * 4);  // 25.6 MB region
    char*  Ar      = (char*)alloc((size_t)N * 80 * 4);  // 32 MB region

    // aliases (strictly sequential lifetimes):
    //  passes A-C:  s32/d32 in Pr, es_tmp in Ar[0..4MB]
    //  pass D:      xb in Ar[4MB..16.8MB]
    //  l1_fused:    reads xb, writes A = Pr[0..16MB]          (disjoint regions)
    //  GEMM2:       reads A (Pr), writes Pb = Ar[0..8MB]      (xb dead)
    //  gather40-L2: reads Pb, writes Ab = Ar[24MB..32MB]
    //  gather40-L3: reads Ab, writes P3 = Pr[0..8MB]          (A dead)
    //  l3head:      reads P3
    int*      s32    = (int*)Pr;
    int*      d32    = (int*)Pr + E;
    unsigned* es_tmp = (unsigned*)Ar;
    size_t xb_off = (((size_t)E * 4) + 255) & ~(size_t)255;
    unsigned short* xb = (unsigned short*)(Ar + xb_off);
    unsigned short* A  = (unsigned short*)Pr;
    unsigned short* Pb = (unsigned short*)Ar;
    unsigned short* Ab = (unsigned short*)(Ar + (size_t)N * 80 * 4 - (size_t)N * 40 * 2);
    unsigned short* P3 = (unsigned short*)Pr;

    const int B = 256;

    // ---- W-fragment prepack (independent of CSR build) ----
    prep_wfrags_kernel<<<10, B, 0, stream>>>(W1, W2, wfrag);

    // ---- CSR build: atomic-free counting sort (+fused x->bf16 cvt) ----
    bucket_count_kernel<<<nblk, B, 0, stream>>>(ei, s32, d32, gcount, E, nblk, nbuk, ch);
    bucket_total_kernel<<<nbuk, B, 0, stream>>>(gcount, btot, nblk);
    scan_btot_kernel<<<1, 512, 0, stream>>>(btot, bbase, row_ofs, nbuk, N, E);
    scan_gcount_kernel<<<nbuk, B, 0, stream>>>(gcount, bbase, nblk);
    bucket_scatter_kernel<<<nblk, B, 0, stream>>>(s32, d32, gcount, es_tmp, E, nblk, nbuk, ch);
    bucket_sortcvt_kernel<<<nbuk, B, 0, stream>>>(es_tmp, bbase, es, row_ofs, dinv,
                                                  x, (ushort4*)xb, N);

    const int blk40 = ((N + 11) / 12 + 3) / 4;   // 12 nodes/wave, 4 waves/block
    const int ntiles = (N + 15) / 16;
    const int gemm_blocks = (ntiles + 3) / 4;

    // L1 fused (K-pair split): gather64 + GEMM1 (+b1 + leaky) -> A bf16
    l1_fused_kernel<<<gemm_blocks, 512, 0, stream>>>(xb, es, row_ofs, dinv, wfrag, b1, A, N);

    // L2: MFMA GEMM2: Pb = bf16((A@W2)*dinv); gather(+b2) -> leaky*dinv -> Ab
    gemm_mfma_bf16<80, 40, 3, 3, false, false, true>
        <<<gemm_blocks, B, 0, stream>>>(A, wfrag + 20 * 512, nullptr, dinv, Pb, N);
    gather40_bf16_kernel<true, true><<<blk40, B, 0, stream>>>(Pb, es, row_ofs, dinv, b2, Ab, N);

    // L3: agg(Ab) -> P3 bf16, then fused GEMM+head
    gather40_bf16_kernel<false, false><<<blk40, B, 0, stream>>>(Ab, es, row_ofs, dinv, nullptr, P3, N);
    l3head_kernel<<<(N + B - 1) / B, B, 0, stream>>>(P3, W3, b3, Wl, bl, out, N);
}

// Round 10
// 254.052 us; speedup vs baseline: 1.0528x; 1.0528x over previous
//
#include <hip/hip_runtime.h>

#define LEAKY(v) ((v) > 0.0f ? (v) : 0.01f * (v))
#define NBUK_MAX 512  // supports N <= 131072 (bucket = dst >> 8); N < 2^24 for packing

typedef __attribute__((ext_vector_type(8))) short bf16x8;   // 8 bf16 = 4 VGPRs
typedef __attribute__((ext_vector_type(4))) float f32x4;    // MFMA accumulator

// ---- bf16 helpers ----------------------------------------------------------
__device__ __forceinline__ unsigned short f2bf(float f) {
    unsigned u = __float_as_uint(f);
    u += 0x7fffu + ((u >> 16) & 1u);  // round-to-nearest-even
    return (unsigned short)(u >> 16);
}
__device__ __forceinline__ unsigned pack2bf(float lo, float hi) {
    return (unsigned)f2bf(lo) | ((unsigned)f2bf(hi) << 16);
}
__device__ __forceinline__ float4 bf4_to_f4(uint2 u) {
    float4 r;
    r.x = __uint_as_float(u.x << 16);
    r.y = __uint_as_float(u.x & 0xffff0000u);
    r.z = __uint_as_float(u.y << 16);
    r.w = __uint_as_float(u.y & 0xffff0000u);
    return r;
}

// ---------------------------------------------------------------------------
// int64-vs-int32 edge_index detection.
// ---------------------------------------------------------------------------
__device__ __forceinline__ int detect_is64(const unsigned* ei, int E) {
    __shared__ int is64_s;
    if (threadIdx.x == 0) {
        int z = 1;
        int limit = 2 * E < 128 ? 2 * E : 128;
        for (int i = 1; i < limit; i += 2)
            if (ei[i] != 0u) { z = 0; break; }
        is64_s = z;
    }
    __syncthreads();
    return is64_s;
}

// ---------------------------------------------------------------------------
// Pass A: decode edge_index -> s32/d32 (coalesced) + per-block bucket counts.
// ---------------------------------------------------------------------------
__global__ __launch_bounds__(256) void bucket_count_kernel(
    const unsigned* __restrict__ ei, int* __restrict__ s32, int* __restrict__ d32,
    int* __restrict__ gcount, int E, int nblk, int nbuk, int ch) {
    __shared__ int hist[NBUK_MAX];
    int is64 = detect_is64(ei, E);
    for (int i = threadIdx.x; i < nbuk; i += 256) hist[i] = 0;
    __syncthreads();
    int base = blockIdx.x * ch;
    int lim = min(base + ch, E);
    for (int e = base + threadIdx.x; e < lim; e += 256) {
        int s, d;
        if (is64) {
            s = (int)ei[2 * (size_t)e];
            d = (int)ei[2 * (size_t)E + 2 * (size_t)e];
        } else {
            s = (int)ei[e];
            d = (int)ei[(size_t)E + e];
        }
        s32[e] = s;
        d32[e] = d;
        atomicAdd(&hist[d >> 8], 1);
    }
    __syncthreads();
    for (int i = threadIdx.x; i < nbuk; i += 256)
        gcount[(size_t)i * nblk + blockIdx.x] = hist[i];
}

// Pass B1: per-bucket totals (one block per bucket, parallel tree reduce).
__global__ __launch_bounds__(256) void bucket_total_kernel(
    const int* __restrict__ gcount, int* __restrict__ btot, int nblk) {
    __shared__ int s[256];
    int sum = 0;
    for (int i = threadIdx.x; i < nblk; i += 256)
        sum += gcount[(size_t)blockIdx.x * nblk + i];
    s[threadIdx.x] = sum;
    __syncthreads();
    for (int off = 128; off > 0; off >>= 1) {
        if (threadIdx.x < off) s[threadIdx.x] += s[threadIdx.x + off];
        __syncthreads();
    }
    if (threadIdx.x == 0) btot[blockIdx.x] = s[0];
}

// Pass B2: exclusive scan of bucket totals -> bbase[0..nbuk], + row_ofs[N]=E.
__global__ __launch_bounds__(512) void scan_btot_kernel(
    const int* __restrict__ btot, int* __restrict__ bbase,
    int* __restrict__ row_ofs, int nbuk, int N, int E) {
    __shared__ int s[512];
    int t = threadIdx.x;
    int v = (t < nbuk) ? btot[t] : 0;
    s[t] = v;
    __syncthreads();
    for (int off = 1; off < 512; off <<= 1) {
        int add = (t >= off) ? s[t - off] : 0;
        __syncthreads();
        s[t] += add;
        __syncthreads();
    }
    if (t < nbuk) bbase[t] = s[t] - v;
    if (t == 0) { bbase[nbuk] = E; row_ofs[N] = E; }
}

// Pass B3: per-bucket exclusive scan of gcount row + bucket base (in place).
__global__ __launch_bounds__(256) void scan_gcount_kernel(
    int* __restrict__ gcount, const int* __restrict__ bbase, int nblk) {
    __shared__ int s[256];
    int t = threadIdx.x;
    int v = (t < nblk) ? gcount[(size_t)blockIdx.x * nblk + t] : 0;
    s[t] = v;
    __syncthreads();
    for (int off = 1; off < 256; off <<= 1) {
        int add = (t >= off) ? s[t - off] : 0;
        __syncthreads();
        s[t] += add;
        __syncthreads();
    }
    if (t < nblk)
        gcount[(size_t)blockIdx.x * nblk + t] = bbase[blockIdx.x] + s[t] - v;
}

// Pass C: scatter edges into bucket-grouped PACKED es_tmp = (d&255)<<24 | src.
__global__ __launch_bounds__(256) void bucket_scatter_kernel(
    const int* __restrict__ s32, const int* __restrict__ d32,
    const int* __restrict__ gofs, unsigned* __restrict__ es_tmp,
    int E, int nblk, int nbuk, int ch) {
    __shared__ int cur[NBUK_MAX];
    for (int i = threadIdx.x; i < nbuk; i += 256)
        cur[i] = gofs[(size_t)i * nblk + blockIdx.x];
    __syncthreads();
    int base = blockIdx.x * ch;
    int lim = min(base + ch, E);
    for (int e = base + threadIdx.x; e < lim; e += 256) {
        int s = s32[e], d = d32[e];
        int p = atomicAdd(&cur[d >> 8], 1);
        es_tmp[p] = ((unsigned)(d & 255) << 24) | (unsigned)s;
    }
}

// Pass D (+cvt fused): per-bucket node counting sort -> es, row_ofs, dinv;
// then converts this bucket's 256 x-rows to xb = bf16(x * dinv).
__global__ __launch_bounds__(256) void bucket_sortcvt_kernel(
    const unsigned* __restrict__ es_tmp, const int* __restrict__ bbase,
    int* __restrict__ es, int* __restrict__ row_ofs, float* __restrict__ dinv,
    const float* __restrict__ x, ushort4* __restrict__ xb, int N) {
    __shared__ int hist[256];
    __shared__ int lofs[256];
    __shared__ float sdinv[256];
    int b = blockIdx.x;
    int t = threadIdx.x;
    int beg = bbase[b], end = bbase[b + 1];
    hist[t] = 0;
    __syncthreads();
    for (int j = beg + t; j < end; j += 256)
        atomicAdd(&hist[es_tmp[j] >> 24], 1);
    __syncthreads();
    int v = hist[t];
    lofs[t] = v;
    __syncthreads();
    for (int off = 1; off < 256; off <<= 1) {
        int add = (t >= off) ? lofs[t - off] : 0;
        __syncthreads();
        lofs[t] += add;
        __syncthreads();
    }
    int excl = lofs[t] - v;
    int node = (b << 8) + t;
    float dv = rsqrtf((float)v + 1.0f);
    if (node <= N) row_ofs[node] = beg + excl;
    if (node < N) dinv[node] = dv;
    sdinv[t] = dv;
    __syncthreads();
    lofs[t] = beg + excl;  // running cursor
    __syncthreads();
    for (int j = beg + t; j < end; j += 256) {
        unsigned ed = es_tmp[j];
        int p = atomicAdd(&lofs[ed >> 24], 1);
        es[p] = (int)(ed & 0xFFFFFFu);
    }
    // cvt: xb rows for this bucket's nodes (16 float4-quads per node)
    int qbase = (b << 8) * 16;
    for (int q = t; q < 256 * 16; q += 256) {
        int nl = q >> 4;
        int n = (b << 8) + nl;
        if (n >= N) break;
        float dn = sdinv[nl];
        float4 vv = ((const float4*)x)[qbase + q];
        ushort4 o;
        o.x = f2bf(vv.x * dn); o.y = f2bf(vv.y * dn);
        o.z = f2bf(vv.z * dn); o.w = f2bf(vv.w * dn);
        xb[qbase + q] = o;
    }
}

// ---------------------------------------------------------------------------
// W-fragment prepack for MFMA GEMMs, with hi/lo bf16 split (W ~ hi + lo so
// the MFMA pair reproduces fp32-W precision).
// Fragment order: f = (mt*NKC + kc)*2 + s; per frag: 64 lanes x 8 bf16.
// Element (lane, j): k = kc*32 + (lane>>4)*8 + j, col = mt*16 + (lane&15).
// Region G1 (W1 64x80, NKC=2, NMT=5): units 0..1279  (frags 0..19).
// Region G2 (W2 80x40, NKC=3, NMT=3): units 1280..2431 (frags 20..37).
// ---------------------------------------------------------------------------
__global__ __launch_bounds__(256) void prep_wfrags_kernel(
    const float* __restrict__ W1, const float* __restrict__ W2,
    unsigned short* __restrict__ wfrag) {
    int t = blockIdx.x * 256 + threadIdx.x;
    if (t >= 2432) return;
    const float* W;
    int u, NKC, M, K;
    if (t < 1280) { u = t; W = W1; NKC = 2; M = 80; K = 64; }
    else          { u = t - 1280; W = W2; NKC = 3; M = 40; K = 80; }
    int f = u >> 6, lane = u & 63;
    int s = f & 1, mtkc = f >> 1;
    int kc = mtkc % NKC, mt = mtkc / NKC;
    int col = mt * 16 + (lane & 15);
#pragma unroll
    for (int j = 0; j < 8; ++j) {
        int k = kc * 32 + ((lane >> 4) << 3) + j;
        float w = (k < K && col < M) ? W[k * M + col] : 0.0f;
        unsigned short hi = f2bf(w);
        unsigned short v = s ? f2bf(w - __uint_as_float((unsigned)hi << 16)) : hi;
        wfrag[(size_t)t * 8 + j] = v;
    }
}

// ---------------------------------------------------------------------------
// FUSED L1+L2GEMM: gather64(xb) + MFMA GEMM1 (+b1, leaky) + MFMA GEMM2 (*dinv)
// -> Pb bf16 [N][40].  One wave = one 16-node tile (round-8 gather structure,
// unroll x4).  A-tile (16x80 bf16) round-trips through a PER-WAVE private LDS
// tile (stride 88: 16B-aligned b128 reads, <=4-way banks) -- no barrier.
// ---------------------------------------------------------------------------
__global__ __launch_bounds__(256) void l1l2_fused_kernel(
    const unsigned short* __restrict__ xb, const int* __restrict__ es,
    const int* __restrict__ row_ofs, const float* __restrict__ dinv,
    const unsigned short* __restrict__ wfrag, const float* __restrict__ b1,
    unsigned short* __restrict__ Pb, int N) {
    constexpr int NFR = 38;  // 20 (W1) + 18 (W2) hi/lo fragments
    __shared__ bf16x8 wlds[NFR * 64];
    __shared__ unsigned short atile[4][16 * 88];  // per-wave A-tile, stride 88
    for (int i = threadIdx.x; i < NFR * 64; i += 256) {
        int f = i >> 6, ln = i & 63;
        wlds[f * 64 + (ln ^ (ln >> 3))] = *(const bf16x8*)&wfrag[(size_t)i * 8];
    }
    __syncthreads();
    int wid = blockIdx.x * 4 + (threadIdx.x >> 6);
    int ntiles = (N + 15) >> 4;
    if (wid >= ntiles) return;
    int lane = threadIdx.x & 63;
    int row = lane & 15, kid = lane >> 4;
    int lidx = lane ^ (lane >> 3);
    int base = wid * 16;
    int node = base + row;
    bool act = node < N;
    int beg = 0, end = 0;
    float dd = 0.f;
    if (act) {
        beg = row_ofs[node];
        end = row_ofs[node + 1];
        dd = dinv[node];
    }
    const char* xbb = (const char*)xb;
    const int o0 = kid * 16;       // byte offset of chunk kid
    const int o1 = 64 + kid * 16;  // byte offset of chunk kid+4
    float4 aL0 = make_float4(0.f, 0.f, 0.f, 0.f);
    float4 aL1 = make_float4(0.f, 0.f, 0.f, 0.f);
    float4 aH0 = make_float4(0.f, 0.f, 0.f, 0.f);
    float4 aH1 = make_float4(0.f, 0.f, 0.f, 0.f);
#define ACCU(u, c0, c1)                                             \
    {                                                               \
        float4 lo_ = bf4_to_f4(make_uint2((u).x, (u).y));           \
        float4 hi_ = bf4_to_f4(make_uint2((u).z, (u).w));           \
        c0.x += lo_.x; c0.y += lo_.y; c0.z += lo_.z; c0.w += lo_.w; \
        c1.x += hi_.x; c1.y += hi_.y; c1.z += hi_.z; c1.w += hi_.w; \
    }
    int j = beg;
    for (; j + 4 <= end; j += 4) {
        int s0 = es[j], s1 = es[j + 1], s2 = es[j + 2], s3 = es[j + 3];
        const char* p0 = xbb + (size_t)s0 * 128;
        const char* p1 = xbb + (size_t)s1 * 128;
        const char* p2 = xbb + (size_t)s2 * 128;
        const char* p3 = xbb + (size_t)s3 * 128;
        uint4 u00 = *(const uint4*)(p0 + o0);
        uint4 u01 = *(const uint4*)(p0 + o1);
        uint4 u10 = *(const uint4*)(p1 + o0);
        uint4 u11 = *(const uint4*)(p1 + o1);
        uint4 u20 = *(const uint4*)(p2 + o0);
        uint4 u21 = *(const uint4*)(p2 + o1);
        uint4 u30 = *(const uint4*)(p3 + o0);
        uint4 u31 = *(const uint4*)(p3 + o1);
        ACCU(u00, aL0, aL1) ACCU(u01, aH0, aH1)
        ACCU(u10, aL0, aL1) ACCU(u11, aH0, aH1)
        ACCU(u20, aL0, aL1) ACCU(u21, aH0, aH1)
        ACCU(u30, aL0, aL1) ACCU(u31, aH0, aH1)
    }
    for (; j < end; ++j) {
        int s0 = es[j];
        const char* p0 = xbb + (size_t)s0 * 128;
        uint4 u00 = *(const uint4*)(p0 + o0);
        uint4 u01 = *(const uint4*)(p0 + o1);
        ACCU(u00, aL0, aL1) ACCU(u01, aH0, aH1)
    }
    if (act) {  // self term
        const char* ps = xbb + (size_t)node * 128;
        uint4 us0 = *(const uint4*)(ps + o0);
        uint4 us1 = *(const uint4*)(ps + o1);
        ACCU(us0, aL0, aL1) ACCU(us1, aH0, aH1)
    }
#undef ACCU
    // pack A-fragments: a0 = chunk kid (kc=0), a1 = chunk kid+4 (kc=1)
    bf16x8 a0, a1;
    a0[0] = (short)f2bf(aL0.x * dd); a0[1] = (short)f2bf(aL0.y * dd);
    a0[2] = (short)f2bf(aL0.z * dd); a0[3] = (short)f2bf(aL0.w * dd);
    a0[4] = (short)f2bf(aL1.x * dd); a0[5] = (short)f2bf(aL1.y * dd);
    a0[6] = (short)f2bf(aL1.z * dd); a0[7] = (short)f2bf(aL1.w * dd);
    a1[0] = (short)f2bf(aH0.x * dd); a1[1] = (short)f2bf(aH0.y * dd);
    a1[2] = (short)f2bf(aH0.z * dd); a1[3] = (short)f2bf(aH0.w * dd);
    a1[4] = (short)f2bf(aH1.x * dd); a1[5] = (short)f2bf(aH1.y * dd);
    a1[6] = (short)f2bf(aH1.z * dd); a1[7] = (short)f2bf(aH1.w * dd);

    // ---- GEMM1: X@W1 (hi+lo) ----
    f32x4 acc[5];
#pragma unroll
    for (int mt = 0; mt < 5; ++mt) acc[mt] = (f32x4){0.f, 0.f, 0.f, 0.f};
#pragma unroll
    for (int mt = 0; mt < 5; ++mt) {
        acc[mt] = __builtin_amdgcn_mfma_f32_16x16x32_bf16(
            a0, wlds[((mt * 2 + 0) * 2 + 0) * 64 + lidx], acc[mt], 0, 0, 0);
        acc[mt] = __builtin_amdgcn_mfma_f32_16x16x32_bf16(
            a0, wlds[((mt * 2 + 0) * 2 + 1) * 64 + lidx], acc[mt], 0, 0, 0);
        acc[mt] = __builtin_amdgcn_mfma_f32_16x16x32_bf16(
            a1, wlds[((mt * 2 + 1) * 2 + 0) * 64 + lidx], acc[mt], 0, 0, 0);
        acc[mt] = __builtin_amdgcn_mfma_f32_16x16x32_bf16(
            a1, wlds[((mt * 2 + 1) * 2 + 1) * 64 + lidx], acc[mt], 0, 0, 0);
    }
    // ---- epilogue 1: A = leaky(acc + b1), transpose via per-wave LDS ----
    unsigned short* at = atile[threadIdx.x >> 6];
#pragma unroll
    for (int mt = 0; mt < 5; ++mt) {
        int col = mt * 16 + (lane & 15);
        float bb = b1[col];
#pragma unroll
        for (int r = 0; r < 4; ++r) {
            float v = acc[mt][r] + bb;
            v = LEAKY(v);
            at[(kid * 4 + r) * 88 + col] = f2bf(v);  // crow = kid*4+r
        }
    }
    // wave-private LDS: compiler orders write->read via lgkmcnt; no barrier.
    bf16x8 a2[3];
#pragma unroll
    for (int kc = 0; kc < 3; ++kc) {
        int k0 = kc * 32 + kid * 8;
        if (k0 + 8 <= 80)
            a2[kc] = *(const bf16x8*)&at[(lane & 15) * 88 + k0];
        else
            a2[kc] = (bf16x8){0, 0, 0, 0, 0, 0, 0, 0};
    }
    // ---- GEMM2: A@W2 (hi+lo), frags 20..37 ----
    f32x4 acc2[3];
#pragma unroll
    for (int mt = 0; mt < 3; ++mt) acc2[mt] = (f32x4){0.f, 0.f, 0.f, 0.f};
#pragma unroll
    for (int mt = 0; mt < 3; ++mt) {
#pragma unroll
        for (int kc = 0; kc < 3; ++kc) {
            acc2[mt] = __builtin_amdgcn_mfma_f32_16x16x32_bf16(
                a2[kc], wlds[(20 + (mt * 3 + kc) * 2 + 0) * 64 + lidx], acc2[mt], 0, 0, 0);
            acc2[mt] = __builtin_amdgcn_mfma_f32_16x16x32_bf16(
                a2[kc], wlds[(20 + (mt * 3 + kc) * 2 + 1) * 64 + lidx], acc2[mt], 0, 0, 0);
        }
    }
    // ---- epilogue 2: Pb = bf16(acc2 * dinv[row]) ----
    float dvr[4];
#pragma unroll
    for (int r = 0; r < 4; ++r)
        dvr[r] = dinv[min(base + kid * 4 + r, N - 1)];
#pragma unroll
    for (int mt = 0; mt < 3; ++mt) {
        int col = mt * 16 + (lane & 15);
        if (col >= 40) continue;
#pragma unroll
        for (int r = 0; r < 4; ++r) {
            int orow = base + kid * 4 + r;
            if (orow < N)
                Pb[(size_t)orow * 40 + col] = f2bf(acc2[mt][r] * dvr[r]);
        }
    }
}

// ---------------------------------------------------------------------------
// F=40 bf16 gather, GROUP-PER-NODE, unroll x4 (4 loads in flight):
// 12 groups x 5 lanes x uint4 (16B) = one 80B row per group; lanes 60-63 idle.
// ---------------------------------------------------------------------------
template <bool BIAS, bool PRESCALE_LEAKY>
__global__ __launch_bounds__(256) void gather40_bf16_kernel(
    const unsigned short* __restrict__ hb, const int* __restrict__ es,
    const int* __restrict__ row_ofs, const float* __restrict__ dinv,
    const float* __restrict__ b, unsigned short* __restrict__ agg, int N) {
    int wid = (blockIdx.x * blockDim.x + threadIdx.x) >> 6;
    int lane = threadIdx.x & 63;
    int g = lane / 5;           // 0..12 (lanes 60-63: g==12, inactive)
    int l = lane - g * 5;       // 0..4
    int node = wid * 12 + g;
    bool active = (g < 12) && (node < N);
    int beg = 0, end = 0;
    float dd = 0.f;
    if (active) {
        beg = row_ofs[node];
        end = row_ofs[node + 1];
        dd = dinv[node];
    }
    float4 aL = make_float4(0.f, 0.f, 0.f, 0.f);
    float4 aH = make_float4(0.f, 0.f, 0.f, 0.f);
#define ACC40(u)                                                    \
    {                                                               \
        float4 lo_ = bf4_to_f4(make_uint2((u).x, (u).y));           \
        float4 hi_ = bf4_to_f4(make_uint2((u).z, (u).w));           \
        aL.x += lo_.x; aL.y += lo_.y; aL.z += lo_.z; aL.w += lo_.w; \
        aH.x += hi_.x; aH.y += hi_.y; aH.z += hi_.z; aH.w += hi_.w; \
    }
    int j = beg;
    for (; j + 4 <= end; j += 4) {
        int s0 = es[j], s1 = es[j + 1], s2 = es[j + 2], s3 = es[j + 3];
        uint4 h0 = *(const uint4*)&hb[(size_t)s0 * 40 + 8 * l];
        uint4 h1 = *(const uint4*)&hb[(size_t)s1 * 40 + 8 * l];
        uint4 h2 = *(const uint4*)&hb[(size_t)s2 * 40 + 8 * l];
        uint4 h3 = *(const uint4*)&hb[(size_t)s3 * 40 + 8 * l];
        ACC40(h0) ACC40(h1) ACC40(h2) ACC40(h3)
    }
    for (; j < end; ++j) {
        int s0 = es[j];
        uint4 h0 = *(const uint4*)&hb[(size_t)s0 * 40 + 8 * l];
        ACC40(h0)
    }
#undef ACC40
    if (active) {
        uint4 sr = *(const uint4*)&hb[(size_t)node * 40 + 8 * l];
        float4 sL = bf4_to_f4(make_uint2(sr.x, sr.y));
        float4 sH = bf4_to_f4(make_uint2(sr.z, sr.w));
        float r0 = (aL.x + sL.x) * dd, r1 = (aL.y + sL.y) * dd;
        float r2 = (aL.z + sL.z) * dd, r3 = (aL.w + sL.w) * dd;
        float r4 = (aH.x + sH.x) * dd, r5 = (aH.y + sH.y) * dd;
        float r6 = (aH.z + sH.z) * dd, r7 = (aH.w + sH.w) * dd;
        if (BIAS) {
            float4 b0 = *(const float4*)&b[8 * l];
            float4 b1 = *(const float4*)&b[8 * l + 4];
            r0 += b0.x; r1 += b0.y; r2 += b0.z; r3 += b0.w;
            r4 += b1.x; r5 += b1.y; r6 += b1.z; r7 += b1.w;
        }
        if (PRESCALE_LEAKY) {
            r0 = LEAKY(r0) * dd; r1 = LEAKY(r1) * dd;
            r2 = LEAKY(r2) * dd; r3 = LEAKY(r3) * dd;
            r4 = LEAKY(r4) * dd; r5 = LEAKY(r5) * dd;
            r6 = LEAKY(r6) * dd; r7 = LEAKY(r7) * dd;
        }
        uint4 o;
        o.x = pack2bf(r0, r1); o.y = pack2bf(r2, r3);
        o.z = pack2bf(r4, r5); o.w = pack2bf(r6, r7);
        *(uint4*)&agg[(size_t)node * 40 + 8 * l] = o;
    }
}

// ---------------------------------------------------------------------------
// Fused L3-GEMM (40->50, +b3) + leaky + head (50x10, +bl) + log_softmax.
// ---------------------------------------------------------------------------
__global__ __launch_bounds__(256) void l3head_kernel(
    const unsigned short* __restrict__ P, const float* __restrict__ W3,
    const float* __restrict__ b3, const float* __restrict__ Wl,
    const float* __restrict__ bl, float* __restrict__ out, int N) {
    __shared__ float w3s[40 * 50];
    __shared__ float b3s[50];
    __shared__ float wls[50 * 10];
    __shared__ float bls[10];
    for (int i = threadIdx.x; i < 2000; i += 256) w3s[i] = W3[i];
    for (int i = threadIdx.x; i < 500; i += 256) wls[i] = Wl[i];
    if (threadIdx.x < 50) b3s[threadIdx.x] = b3[threadIdx.x];
    if (threadIdx.x < 10) bls[threadIdx.x] = bl[threadIdx.x];
    __syncthreads();
    int n = blockIdx.x * blockDim.x + threadIdx.x;
    if (n >= N) return;

    float p[40];
    const uint2* pr = (const uint2*)(P + (size_t)n * 40);
#pragma unroll
    for (int q = 0; q < 10; ++q) {
        float4 t = bf4_to_f4(pr[q]);
        p[4 * q + 0] = t.x; p[4 * q + 1] = t.y; p[4 * q + 2] = t.z; p[4 * q + 3] = t.w;
    }
    float logits[10];
#pragma unroll
    for (int j = 0; j < 10; ++j) logits[j] = bls[j];
    for (int m = 0; m < 50; ++m) {
        float acc = b3s[m];
#pragma unroll
        for (int k = 0; k < 40; ++k) acc = fmaf(p[k], w3s[k * 50 + m], acc);
        float v = LEAKY(acc);
#pragma unroll
        for (int j = 0; j < 10; ++j) logits[j] = fmaf(v, wls[m * 10 + j], logits[j]);
    }
    float mx = logits[0];
#pragma unroll
    for (int j = 1; j < 10; ++j) mx = fmaxf(mx, logits[j]);
    float s = 0.0f;
#pragma unroll
    for (int j = 0; j < 10; ++j) s += __expf(logits[j] - mx);
    float lse = __logf(s) + mx;
    float* op = out + (size_t)n * 10;
#pragma unroll
    for (int j = 0; j < 10; ++j) op[j] = logits[j] - lse;
}

extern "C" void kernel_launch(void* const* d_in, const int* in_sizes, int n_in,
                              void* d_out, int out_size, void* d_ws, size_t ws_size,
                              hipStream_t stream) {
    const float* x  = (const float*)d_in[0];
    const unsigned* ei = (const unsigned*)d_in[1];
    const float* W1 = (const float*)d_in[2];
    const float* b1 = (const float*)d_in[3];
    const float* W2 = (const float*)d_in[4];
    const float* b2 = (const float*)d_in[5];
    const float* W3 = (const float*)d_in[6];
    const float* b3 = (const float*)d_in[7];
    const float* Wl = (const float*)d_in[8];
    const float* bl = (const float*)d_in[9];
    float* out = (float*)d_out;

    const int N = in_sizes[0] / 64;
    const int E = in_sizes[1] / 2;

    // counting-sort geometry
    int ch = 4096;
    int nblk = (E + ch - 1) / ch;
    if (nblk > 256) { ch = (E + 255) / 256; nblk = (E + ch - 1) / ch; }
    const int nbuk = (N + 255) >> 8;  // <= 512

    char* wp = (char*)d_ws;
    auto alloc = [&](size_t bytes) {
        char* p = wp;
        wp += (bytes + 255) & ~(size_t)255;
        return p;
    };
    int*   es      = (int*)alloc((size_t)E * 4);
    float* dinv    = (float*)alloc((size_t)N * 4);
    int*   row_ofs = (int*)alloc((size_t)(N + 1) * 4);
    int*   gcount  = (int*)alloc((size_t)nbuk * nblk * 4);
    int*   btot    = (int*)alloc((size_t)NBUK_MAX * 4);
    int*   bbase   = (int*)alloc((size_t)(NBUK_MAX + 1) * 4);
    unsigned short* wfrag = (unsigned short*)alloc((size_t)2432 * 8 * 2);  // 38 KB
    char*  Pr      = (char*)alloc((size_t)N * 64 * 4);  // 25.6 MB region
    char*  Ar      = (char*)alloc((size_t)N * 80 * 4);  // 32 MB region

    // aliases (strictly sequential lifetimes):
    //  passes A-C:   s32/d32 in Pr, es_tmp in Ar[0..4MB]
    //  pass D:       xb in Ar[4MB..16.8MB]
    //  l1l2_fused:   reads xb (Ar), writes Pb = Pr[0..8MB]    (disjoint regions)
    //  gather40-L2:  reads Pb (Pr), writes Ab = Ar[24MB..32MB] (xb dead)
    //  gather40-L3:  reads Ab, writes P3 = Pr[0..8MB]          (Pb dead)
    //  l3head:       reads P3
    int*      s32    = (int*)Pr;
    int*      d32    = (int*)Pr + E;
    unsigned* es_tmp = (unsigned*)Ar;
    size_t xb_off = (((size_t)E * 4) + 255) & ~(size_t)255;
    unsigned short* xb = (unsigned short*)(Ar + xb_off);
    unsigned short* Pb = (unsigned short*)Pr;
    unsigned short* Ab = (unsigned short*)(Ar + (size_t)N * 80 * 4 - (size_t)N * 40 * 2);
    unsigned short* P3 = (unsigned short*)Pr;

    const int B = 256;

    // ---- W-fragment prepack (independent of CSR build) ----
    prep_wfrags_kernel<<<10, B, 0, stream>>>(W1, W2, wfrag);

    // ---- CSR build: atomic-free counting sort (+fused x->bf16 cvt) ----
    bucket_count_kernel<<<nblk, B, 0, stream>>>(ei, s32, d32, gcount, E, nblk, nbuk, ch);
    bucket_total_kernel<<<nbuk, B, 0, stream>>>(gcount, btot, nblk);
    scan_btot_kernel<<<1, 512, 0, stream>>>(btot, bbase, row_ofs, nbuk, N, E);
    scan_gcount_kernel<<<nbuk, B, 0, stream>>>(gcount, bbase, nblk);
    bucket_scatter_kernel<<<nblk, B, 0, stream>>>(s32, d32, gcount, es_tmp, E, nblk, nbuk, ch);
    bucket_sortcvt_kernel<<<nbuk, B, 0, stream>>>(es_tmp, bbase, es, row_ofs, dinv,
                                                  x, (ushort4*)xb, N);

    const int blk40 = ((N + 11) / 12 + 3) / 4;   // 12 nodes/wave, 4 waves/block
    const int ntiles = (N + 15) / 16;
    const int gemm_blocks = (ntiles + 3) / 4;

    // L1+L2GEMM fused: gather64 + GEMM1(+b1,leaky) + GEMM2(*dinv) -> Pb bf16
    l1l2_fused_kernel<<<gemm_blocks, B, 0, stream>>>(xb, es, row_ofs, dinv, wfrag, b1, Pb, N);

    // L2 gather: (+b2) -> leaky*dinv -> Ab
    gather40_bf16_kernel<true, true><<<blk40, B, 0, stream>>>(Pb, es, row_ofs, dinv, b2, Ab, N);

    // L3: agg(Ab) -> P3 bf16, then fused GEMM+head
    gather40_bf16_kernel<false, false><<<blk40, B, 0, stream>>>(Ab, es, row_ofs, dinv, nullptr, P3, N);
    l3head_kernel<<<(N + B - 1) / B, B, 0, stream>>>(P3, W3, b3, Wl, bl, out, N);
}